// Round 11
// baseline (89.153 us; speedup 1.0000x reference)
//
#include <hip/hip_runtime.h>

// QSP via Laurent polynomial, TWO kernels.
// u00(theta) = sum_{t=0..127} gamma_t e^{i(2t-127)theta}; gamma depends only on phis.
// Setup (1 wave, DPP recurrence validated R6-R10) -> 64 float4 gammas in d_ws.
// Main: pure-scalar-fma Horner in z = e^{2 i theta}; coefficients via UNIFORM
// s_load_dwordx4 (SGPR src2 into v_fma = free broadcast, no LDS, no barrier).

#define NPHI 128

__device__ __forceinline__ float wave_shr1(float x) {
    // lane L <- lane L-1, lane 0 <- 0 (DPP wave_shr:1, bound_ctrl=1)
    return __builtin_bit_cast(float,
        __builtin_amdgcn_update_dpp(0, __builtin_bit_cast(int, x),
                                    0x138, 0xf, 0xf, true));
}

__global__ __launch_bounds__(64) void qsp_setup(
    const float* __restrict__ phis,
    float4* __restrict__ tab)        // 64 entries: {g_{2L}.r, .i, g_{2L+1}.r, .i}
{
    __shared__ float2 h[NPHI];       // 0.5 * e^{i phi_k}
    const int L = threadIdx.x;

    float sp, cp;
    __sincosf(phis[L], &sp, &cp);
    h[L] = make_float2(0.5f * cp, 0.5f * sp);
    __sincosf(phis[L + 64], &sp, &cp);
    h[L + 64] = make_float2(0.5f * cp, 0.5f * sp);
    __syncthreads();   // single wave: in-order DS

    // lane L holds slots j=2L (A0/B0), j=2L+1 (A1/B1), scalar re/im
    float A0r = 0.f, A0i = 0.f, B0r = 0.f, B0i = 0.f;
    float A1r = 0.f, A1i = 0.f, B1r = 0.f, B1i = 0.f;
    const float2 h0 = h[0];
    if (L == 0) { A0r = 2.f * h0.x; A0i = 2.f * h0.y; }   // A[0] = e_0

    #pragma unroll 4
    for (int k = 1; k < NPHI; ++k) {
        const float2 hk = h[k];
        const float hx = hk.x, hy = hk.y;
        const float pAr = wave_shr1(A1r), pAi = wave_shr1(A1i);
        const float pBr = wave_shr1(B1r), pBi = wave_shr1(B1i);
        const float u0r = pAr + pBr, u0i = pAi + pBi;
        const float v0r = A0r - B0r, v0i = A0i - B0i;
        const float sA0r = u0r + v0r, sA0i = u0i + v0i;
        const float sB0r = u0r - v0r, sB0i = u0i - v0i;
        const float u1r = A0r + B0r, u1i = A0i + B0i;
        const float v1r = A1r - B1r, v1i = A1i - B1i;
        const float sA1r = u1r + v1r, sA1i = u1i + v1i;
        const float sB1r = u1r - v1r, sB1i = u1i - v1i;
        A0r = fmaf(hx, sA0r, -hy * sA0i);
        A0i = fmaf(hx, sA0i,  hy * sA0r);
        B0r = fmaf(hx, sB0r,  hy * sB0i);
        B0i = fmaf(hx, sB0i, -hy * sB0r);
        A1r = fmaf(hx, sA1r, -hy * sA1i);
        A1i = fmaf(hx, sA1i,  hy * sA1r);
        B1r = fmaf(hx, sB1r,  hy * sB1i);
        B1i = fmaf(hx, sB1i, -hy * sB1r);
    }
    tab[L] = make_float4(A0r, A0i, A1r, A1i);   // gamma_{2L}, gamma_{2L+1}
}

__global__ __launch_bounds__(256) void qsp_main(
    const float* __restrict__ th,
    const float4* __restrict__ tab,   // uniform -> s_load_dwordx4
    float* __restrict__ out,          // [0,B): real, [B,2B): imag
    int Bq)                            // B/4
{
    const int idx = blockIdx.x * blockDim.x + threadIdx.x;
    const int lidx = (idx < Bq) ? idx : 0;
    const float4 t4 = ((const float4*)th)[lidx];
    const float th4[4] = {t4.x, t4.y, t4.z, t4.w};

    float zr[4], zi[4];
    #pragma unroll
    for (int e = 0; e < 4; ++e) {
        float s, c;
        __sincosf(2.f * th4[e], &s, &c);
        zr[e] = c; zi[e] = s;
    }

    // Horner, t = 127..0, acc starts 0; coefficients from SGPRs
    float ar[4] = {0.f, 0.f, 0.f, 0.f};
    float ai[4] = {0.f, 0.f, 0.f, 0.f};

    #pragma unroll 8
    for (int jj = NPHI / 2 - 1; jj >= 0; --jj) {
        const float4 gp = tab[jj];       // uniform address -> scalar load
        #pragma unroll
        for (int e = 0; e < 4; ++e) {    // t = 2jj+1: g = (gp.z, gp.w)
            const float nr = fmaf(ar[e], zr[e], fmaf(-ai[e], zi[e], gp.z));
            const float ni = fmaf(ar[e], zi[e], fmaf( ai[e], zr[e], gp.w));
            ar[e] = nr; ai[e] = ni;
        }
        #pragma unroll
        for (int e = 0; e < 4; ++e) {    // t = 2jj: g = (gp.x, gp.y)
            const float nr = fmaf(ar[e], zr[e], fmaf(-ai[e], zi[e], gp.x));
            const float ni = fmaf(ar[e], zi[e], fmaf( ai[e], zr[e], gp.y));
            ar[e] = nr; ai[e] = ni;
        }
    }

    // multiply by e^{-127 i theta}: re = ar*C + ai*S, im = ai*C - ar*S
    float orv[4], oiv[4];
    #pragma unroll
    for (int e = 0; e < 4; ++e) {
        float S, C;
        __sincosf(127.f * th4[e], &S, &C);
        orv[e] = fmaf(ar[e], C,  ai[e] * S);
        oiv[e] = fmaf(ai[e], C, -ar[e] * S);
    }

    if (idx < Bq) {
        float4* o4 = (float4*)out;
        o4[idx]      = make_float4(orv[0], orv[1], orv[2], orv[3]);
        o4[idx + Bq] = make_float4(oiv[0], oiv[1], oiv[2], oiv[3]);
    }
}

extern "C" void kernel_launch(void* const* d_in, const int* in_sizes, int n_in,
                              void* d_out, int out_size, void* d_ws, size_t ws_size,
                              hipStream_t stream)
{
    const float* th   = (const float*)d_in[0];
    const float* phis = (const float*)d_in[1];
    float* out = (float*)d_out;
    float4* tab = (float4*)d_ws;        // 64 * 16 B = 1 KB scratch
    const int B = in_sizes[0];          // 2097152
    const int Bq = B >> 2;              // 524288 threads

    qsp_setup<<<1, 64, 0, stream>>>(phis, tab);

    const int block = 256;
    const int grid = (Bq + block - 1) / block;   // 2048 blocks, 32 waves/CU
    qsp_main<<<grid, block, 0, stream>>>(th, tab, out, Bq);
}

// Round 12
// 87.885 us; speedup vs baseline: 1.0144x; 1.0144x over previous
//
#include <hip/hip_runtime.h>

// QSP via Laurent polynomial, single fused kernel.
// u00(theta) = sum_{t=0..127} gamma_t e^{i(2t-127)theta}; gamma depends only on phis.
// Compressed recurrence (j=(m+k)/2 in [0,k], validated R6-R11):
//   A'[j] = e_k  * 0.5*(A[j-1] + A[j] + B[j-1] - B[j])
//   B'[j] = ek^* * 0.5*(A[j-1] - A[j] + B[j-1] + B[j])
// R12: Horner core in HAND-FORCED v_pk_fma_f32 (inline asm; compiler refuses to
// select VOP3P packed-f32 from generic IR - R1 evidence). 2 elems/instr ->
// hot-loop issue halves vs scalar. Structure otherwise identical to R10
// (best measured): fused, block=256, 8 elems/thread, grid=1024, DPP setup.

#define NPHI 128

typedef float v2f __attribute__((ext_vector_type(2)));

__device__ __forceinline__ float wave_shr1(float x) {
    // lane L <- lane L-1, lane 0 <- 0 (DPP wave_shr:1, bound_ctrl=1)
    return __builtin_bit_cast(float,
        __builtin_amdgcn_update_dpp(0, __builtin_bit_cast(int, x),
                                    0x138, 0xf, 0xf, true));
}

// One Horner step for a packed pair of elements:
//   ar' = ar*zr + (ai*(-zi) + gr) ;  ai' = ar*zi + (ai*zr + gi)
__device__ __forceinline__ void pk_step(v2f& ar, v2f& ai,
                                        const v2f zr, const v2f zi, const v2f nzi,
                                        const v2f gr, const v2f gi) {
    v2f t0, t1, nr, ni;
    asm("v_pk_fma_f32 %0, %1, %2, %3" : "=v"(t0) : "v"(ai), "v"(nzi), "v"(gr));
    asm("v_pk_fma_f32 %0, %1, %2, %3" : "=v"(nr) : "v"(ar), "v"(zr),  "v"(t0));
    asm("v_pk_fma_f32 %0, %1, %2, %3" : "=v"(t1) : "v"(ai), "v"(zr),  "v"(gi));
    asm("v_pk_fma_f32 %0, %1, %2, %3" : "=v"(ni) : "v"(ar), "v"(zi),  "v"(t1));
    ar = nr; ai = ni;
}

__global__ __launch_bounds__(256, 4) void qsp_fused(
    const float* __restrict__ th,
    const float* __restrict__ phis,
    float* __restrict__ out,    // [0,B): real, [B,2B): imag
    int Bq8)                     // B/8
{
    __shared__ alignas(16) float2 g2[NPHI];   // gamma_t
    __shared__ float2 h[NPHI];                // 0.5 * e^{i phi_k}

    const int tid = threadIdx.x;

    if (tid < 64) {
        const int L = tid;
        float sp, cp;
        __sincosf(phis[L], &sp, &cp);
        h[L] = make_float2(0.5f * cp, 0.5f * sp);
        __sincosf(phis[L + 64], &sp, &cp);
        h[L + 64] = make_float2(0.5f * cp, 0.5f * sp);
        // same-wave DS ordering: reads below see these writes

        float A0r = 0.f, A0i = 0.f, B0r = 0.f, B0i = 0.f;
        float A1r = 0.f, A1i = 0.f, B1r = 0.f, B1i = 0.f;
        const float2 h0 = h[0];
        if (L == 0) { A0r = 2.f * h0.x; A0i = 2.f * h0.y; }   // A[0] = e_0

        #pragma unroll 4
        for (int k = 1; k < NPHI; ++k) {
            const float2 hk = h[k];
            const float hx = hk.x, hy = hk.y;
            const float pAr = wave_shr1(A1r), pAi = wave_shr1(A1i);
            const float pBr = wave_shr1(B1r), pBi = wave_shr1(B1i);
            const float u0r = pAr + pBr, u0i = pAi + pBi;
            const float v0r = A0r - B0r, v0i = A0i - B0i;
            const float sA0r = u0r + v0r, sA0i = u0i + v0i;
            const float sB0r = u0r - v0r, sB0i = u0i - v0i;
            const float u1r = A0r + B0r, u1i = A0i + B0i;
            const float v1r = A1r - B1r, v1i = A1i - B1i;
            const float sA1r = u1r + v1r, sA1i = u1i + v1i;
            const float sB1r = u1r - v1r, sB1i = u1i - v1i;
            A0r = fmaf(hx, sA0r, -hy * sA0i);
            A0i = fmaf(hx, sA0i,  hy * sA0r);
            B0r = fmaf(hx, sB0r,  hy * sB0i);
            B0i = fmaf(hx, sB0i, -hy * sB0r);
            A1r = fmaf(hx, sA1r, -hy * sA1i);
            A1i = fmaf(hx, sA1i,  hy * sA1r);
            B1r = fmaf(hx, sB1r,  hy * sB1i);
            B1i = fmaf(hx, sB1i, -hy * sB1r);
        }
        ((float4*)g2)[L] = make_float4(A0r, A0i, A1r, A1i);  // gamma_{2L}, gamma_{2L+1}
    }

    // ---- prologue: gamma-independent, overlaps wave 0's setup ----
    const int idx = blockIdx.x * blockDim.x + tid;
    const int lidx = (idx < Bq8) ? idx : 0;
    const float4 ta = ((const float4*)th)[2 * lidx];
    const float4 tb = ((const float4*)th)[2 * lidx + 1];
    const float th8[8] = {ta.x, ta.y, ta.z, ta.w, tb.x, tb.y, tb.z, tb.w};

    v2f zrp[4], zip[4], nzip[4];
    #pragma unroll
    for (int p = 0; p < 4; ++p) {
        float s0, c0, s1, c1;
        __sincosf(2.f * th8[2 * p],     &s0, &c0);
        __sincosf(2.f * th8[2 * p + 1], &s1, &c1);
        zrp[p]  = (v2f){c0, c1};
        zip[p]  = (v2f){s0, s1};
        nzip[p] = (v2f){-s0, -s1};
    }

    __syncthreads();

    // ---- Horner in z = e^{2 i theta}, t = 127..0, acc starts 0 ----
    v2f arp[4], aip[4];
    #pragma unroll
    for (int p = 0; p < 4; ++p) { arp[p] = (v2f){0.f, 0.f}; aip[p] = (v2f){0.f, 0.f}; }

    const float4* g4 = (const float4*)g2;
    float4 gp = g4[NPHI / 2 - 1];

    #pragma unroll 4
    for (int jj = NPHI / 2 - 1; jj >= 1; --jj) {
        const float4 gn = g4[jj - 1];    // prefetch next pair (independent)
        {   // t = 2jj+1: g = (gp.z, gp.w)
            const v2f gr = {gp.z, gp.z}, gi = {gp.w, gp.w};
            #pragma unroll
            for (int p = 0; p < 4; ++p)
                pk_step(arp[p], aip[p], zrp[p], zip[p], nzip[p], gr, gi);
        }
        {   // t = 2jj: g = (gp.x, gp.y)
            const v2f gr = {gp.x, gp.x}, gi = {gp.y, gp.y};
            #pragma unroll
            for (int p = 0; p < 4; ++p)
                pk_step(arp[p], aip[p], zrp[p], zip[p], nzip[p], gr, gi);
        }
        gp = gn;
    }
    {   // t = 1
        const v2f gr = {gp.z, gp.z}, gi = {gp.w, gp.w};
        #pragma unroll
        for (int p = 0; p < 4; ++p)
            pk_step(arp[p], aip[p], zrp[p], zip[p], nzip[p], gr, gi);
    }
    {   // t = 0
        const v2f gr = {gp.x, gp.x}, gi = {gp.y, gp.y};
        #pragma unroll
        for (int p = 0; p < 4; ++p)
            pk_step(arp[p], aip[p], zrp[p], zip[p], nzip[p], gr, gi);
    }

    // ---- multiply by e^{-127 i theta}: re = ar*C + ai*S, im = ai*C - ar*S ----
    float orv[8], oiv[8];
    #pragma unroll
    for (int e = 0; e < 8; ++e) {
        float S, C;
        __sincosf(127.f * th8[e], &S, &C);
        const float arx = (e & 1) ? arp[e >> 1].y : arp[e >> 1].x;
        const float aix = (e & 1) ? aip[e >> 1].y : aip[e >> 1].x;
        orv[e] = fmaf(arx, C,  aix * S);
        oiv[e] = fmaf(aix, C, -arx * S);
    }

    if (idx < Bq8) {
        float4* o4 = (float4*)out;
        const int ib = 2 * Bq8;   // imag base in float4 units (= B/4)
        o4[2 * idx]          = make_float4(orv[0], orv[1], orv[2], orv[3]);
        o4[2 * idx + 1]      = make_float4(orv[4], orv[5], orv[6], orv[7]);
        o4[ib + 2 * idx]     = make_float4(oiv[0], oiv[1], oiv[2], oiv[3]);
        o4[ib + 2 * idx + 1] = make_float4(oiv[4], oiv[5], oiv[6], oiv[7]);
    }
}

extern "C" void kernel_launch(void* const* d_in, const int* in_sizes, int n_in,
                              void* d_out, int out_size, void* d_ws, size_t ws_size,
                              hipStream_t stream)
{
    const float* th   = (const float*)d_in[0];
    const float* phis = (const float*)d_in[1];
    float* out = (float*)d_out;
    const int B = in_sizes[0];          // 2097152
    const int Bq8 = B >> 3;             // 262144 threads
    const int block = 256;              // 4 waves
    const int grid = (Bq8 + block - 1) / block;   // 1024 blocks = 4/CU, 16 waves/CU
    qsp_fused<<<grid, block, 0, stream>>>(th, phis, out, Bq8);
}